// Round 12
// baseline (283.258 us; speedup 1.0000x reference)
//
#include <hip/hip_runtime.h>
#include <hip/hip_bf16.h>

typedef __attribute__((ext_vector_type(8))) short short8;
typedef __attribute__((ext_vector_type(4))) short short4v;
typedef __attribute__((ext_vector_type(4))) float floatx4;
typedef __attribute__((ext_vector_type(16))) float floatx16;

#define B_ 4
#define T_ 2048
#define C_ 1024
#define H_ 16
#define DK_ 64
#define M_ (B_ * T_)   // 8192
#define N3_ (3 * C_)   // 3072

// scale(1/8) * log2(e): folds softmax scaling AND exp->exp2 conversion into Q
#define QSCALE 0.1803368801111243f

__device__ __forceinline__ unsigned short f2bf(float f) {
    union { float f; unsigned u; } v; v.f = f;
    unsigned r = v.u + 0x7fffu + ((v.u >> 16) & 1u);
    return (unsigned short)(r >> 16);
}
__device__ __forceinline__ unsigned fbits(float f) {
    union { float f; unsigned u; } v; v.f = f; return v.u;
}
// pack two f32 -> dword of two bf16 (lo = a, hi = b)
__device__ __forceinline__ unsigned pack_bf16(float a, float b) {
#if __has_builtin(__builtin_amdgcn_cvt_pk_bf16_f32)
    typedef __attribute__((ext_vector_type(2))) __bf16 bf16x2;
    bf16x2 r = __builtin_amdgcn_cvt_pk_bf16_f32(a, b);
    union { bf16x2 v; unsigned u; } c; c.v = r; return c.u;
#else
    return __builtin_amdgcn_perm(fbits(b) + 0x8000u, fbits(a) + 0x8000u, 0x07060302u);
#endif
}

__device__ __forceinline__ void gload_lds16(const unsigned short* g, unsigned short* l) {
    __builtin_amdgcn_global_load_lds(
        (const __attribute__((address_space(1))) unsigned int*)(const void*)g,
        (__attribute__((address_space(3))) unsigned int*)(void*)l, 16, 0, 0);
}

// ---------------- fused cast fp32 -> bf16 for x, w_attn, w_proj --------------
#define NX4 (M_ * C_ / 4)     // 2097152
#define NA4 (N3_ * C_ / 4)    //  786432
#define NP4 (C_ * C_ / 4)     //  262144
__global__ __launch_bounds__(256) void cast3_kernel(const float* __restrict__ x,
                                                    const float* __restrict__ wa,
                                                    const float* __restrict__ wp,
                                                    unsigned short* __restrict__ xb,
                                                    unsigned short* __restrict__ wab,
                                                    unsigned short* __restrict__ wpb) {
    int i = blockIdx.x * 256 + threadIdx.x;
    const float* src; unsigned short* dst; int j;
    if (i < NX4) { src = x; dst = xb; j = i; }
    else if (i < NX4 + NA4) { src = wa; dst = wab; j = i - NX4; }
    else { src = wp; dst = wpb; j = i - NX4 - NA4; }
    float4 v = ((const float4*)src)[j];
    ushort4 o;
    o.x = f2bf(v.x); o.y = f2bf(v.y); o.z = f2bf(v.z); o.w = f2bf(v.w);
    ((ushort4*)dst)[j] = o;
}

// ---------------- B^T GEMM: m97 structure, BK=64, XOR-swizzled LDS -----------
// (R9/R11-verified: conflicts 0, best total 258.9 us. Unchanged.)
#define BM 128
#define BN 128
#define BK 64
#define ELD 132   // epilogue LDS row stride (shorts)

__global__ __launch_bounds__(256) void gemm_qkv(const unsigned short* __restrict__ A,
                                                const unsigned short* __restrict__ W,
                                                const float* __restrict__ bias,
                                                unsigned short* __restrict__ qout,
                                                unsigned short* __restrict__ kout,
                                                unsigned short* __restrict__ vout) {
    __shared__ unsigned short sh[BM * ELD];     // 33792 B; As/Bs carved below
    unsigned short* As = sh;                    // [128][64]
    unsigned short* Bs = sh + BM * BK;          // [128][64]

    int lin = blockIdx.y * gridDim.x + blockIdx.x;
    int cpx = (gridDim.x * gridDim.y) >> 3;
    int swz = (lin & 7) * cpx + (lin >> 3);
    int m0 = (swz / gridDim.x) * BM;
    int n0 = (swz % gridDim.x) * BN;
    int tid = threadIdx.x;
    int lane = tid & 63, w = tid >> 6;
    int wm = (w >> 1) * 64, wn = (w & 1) * 64;
    int l16 = lane & 15, quad = lane >> 4;
    int srow = lane >> 3;
    int scol = ((lane & 7) ^ srow) * 8;         // pre-swizzled global source chunk

    floatx4 acc[4][4] = {};
    for (int kt = 0; kt < C_; kt += BK) {
        __syncthreads();
        for (int t = 0; t < 4; ++t) {
            int rbase = w * 32 + t * 8;
            gload_lds16(&A[(size_t)(m0 + rbase + srow) * C_ + kt + scol], &As[rbase * BK]);
            gload_lds16(&W[(size_t)(n0 + rbase + srow) * C_ + kt + scol], &Bs[rbase * BK]);
        }
        __syncthreads();
#pragma unroll
        for (int kc = 0; kc < 2; ++kc) {
            int ch = ((kc * 4 + quad) ^ (l16 & 7)) * 8;
            short8 af[4], bf[4];
            for (int i = 0; i < 4; ++i)
                af[i] = *(const short8*)&As[(wm + 16 * i + l16) * BK + ch];
            for (int j = 0; j < 4; ++j)
                bf[j] = *(const short8*)&Bs[(wn + 16 * j + l16) * BK + ch];
            for (int i = 0; i < 4; ++i)
                for (int j = 0; j < 4; ++j)
                    acc[i][j] = __builtin_amdgcn_mfma_f32_16x16x32_bf16(af[i], bf[j], acc[i][j], 0, 0, 0);
        }
    }

    int secb = n0 >> 10;    // block-uniform section (BN=128 divides 1024)
    if (secb == 2) {
        // V transposed: [bh][d][t], 4 consecutive t -> one ushort4
        for (int i = 0; i < 4; ++i)
            for (int j = 0; j < 4; ++j) {
                int col = n0 + wn + 16 * j + l16;
                float bval = bias[col];
                int cc = col & 1023;
                int h = cc >> 6, d = cc & 63;
                int m = m0 + wm + 16 * i + quad * 4;
                int b = m >> 11, t = m & (T_ - 1);
                int bh = b * H_ + h;
                ushort4 o;
                o.x = f2bf(acc[i][j][0] + bval);
                o.y = f2bf(acc[i][j][1] + bval);
                o.z = f2bf(acc[i][j][2] + bval);
                o.w = f2bf(acc[i][j][3] + bval);
                *(ushort4*)&vout[((size_t)bh * DK_ + d) * T_ + t] = o;
            }
    } else {
        float qs = (secb == 0) ? QSCALE : 1.0f;
        unsigned short* dst = (secb == 0) ? qout : kout;
        __syncthreads();
        for (int i = 0; i < 4; ++i)
            for (int j = 0; j < 4; ++j) {
                int col = wn + 16 * j + l16;
                float bval = bias[n0 + col];
                for (int r = 0; r < 4; ++r) {
                    int row = wm + 16 * i + quad * 4 + r;
                    sh[row * ELD + col] = f2bf((acc[i][j][r] + bval) * qs);
                }
            }
        __syncthreads();
        for (int p = 0; p < 8; ++p) {
            int row = p * 16 + (tid >> 4);
            int cl = l16 * 8;
            short8 v = *(const short8*)&sh[row * ELD + cl];
            int cc = (n0 & 1023) + cl;
            int h = cc >> 6, d = cc & 63;
            int m = m0 + row, b = m >> 11, t = m & (T_ - 1);
            int bh = b * H_ + h;
            *(short8*)&dst[((size_t)bh * T_ + t) * DK_ + d] = v;
        }
    }
}

__global__ __launch_bounds__(256) void gemm_proj(const unsigned short* __restrict__ A,
                                                 const unsigned short* __restrict__ W,
                                                 const float* __restrict__ bias,
                                                 float* __restrict__ out) {
    __shared__ unsigned short As[BM * BK];
    __shared__ unsigned short Bs[BN * BK];
    int lin = blockIdx.y * gridDim.x + blockIdx.x;
    int cpx = (gridDim.x * gridDim.y) >> 3;
    int swz = (lin & 7) * cpx + (lin >> 3);
    int m0 = (swz / gridDim.x) * BM;
    int n0 = (swz % gridDim.x) * BN;
    int tid = threadIdx.x;
    int lane = tid & 63, w = tid >> 6;
    int wm = (w >> 1) * 64, wn = (w & 1) * 64;
    int l16 = lane & 15, quad = lane >> 4;
    int srow = lane >> 3;
    int scol = ((lane & 7) ^ srow) * 8;

    floatx4 acc[4][4] = {};
    for (int kt = 0; kt < C_; kt += BK) {
        __syncthreads();
        for (int t = 0; t < 4; ++t) {
            int rbase = w * 32 + t * 8;
            gload_lds16(&A[(size_t)(m0 + rbase + srow) * C_ + kt + scol], &As[rbase * BK]);
            gload_lds16(&W[(size_t)(n0 + rbase + srow) * C_ + kt + scol], &Bs[rbase * BK]);
        }
        __syncthreads();
#pragma unroll
        for (int kc = 0; kc < 2; ++kc) {
            int ch = ((kc * 4 + quad) ^ (l16 & 7)) * 8;
            short8 af[4], bf[4];
            for (int i = 0; i < 4; ++i)
                af[i] = *(const short8*)&As[(wm + 16 * i + l16) * BK + ch];
            for (int j = 0; j < 4; ++j)
                bf[j] = *(const short8*)&Bs[(wn + 16 * j + l16) * BK + ch];
            for (int i = 0; i < 4; ++i)
                for (int j = 0; j < 4; ++j)
                    acc[i][j] = __builtin_amdgcn_mfma_f32_16x16x32_bf16(af[i], bf[j], acc[i][j], 0, 0, 0);
        }
    }
    for (int i = 0; i < 4; ++i)
        for (int j = 0; j < 4; ++j) {
            int col = n0 + wn + 16 * j + l16;
            float bval = bias[col];
            for (int r = 0; r < 4; ++r) {
                int m = m0 + wm + 16 * i + quad * 4 + r;
                out[(size_t)m * C_ + col] = acc[i][j][r] + bval;
            }
        }
}

// ---------------- flash attention: KT=128 (BK=64-analog for attn) ------------
// R11 A/A: attn stable at 82.5 us, ~75% stall, fixed per-iter cost = 2
// barriers + L2 staging latency paid 32x. KT 64->128 halves the event count
// (16 iters) at constant total work — the same mechanism as the verified
// BK 32->64 GEMM win. No register doubling: the two 64-key halves are
// processed SEQUENTIALLY per iteration (S-accumulators/pA/pB reused).
// Same 2-barrier pattern (no sync-structure change). Ks [128][72]; Vts
// [64][136] (136 shorts = 68 dwords ≡ 4 mod 32 — same conflict profile
// as LD=72). LDS 35.8 KB (grid 512 caps at 2 blocks/CU regardless).
#define KT 128
#define LD 72    // Ks row stride (shorts)
#define LDV 136  // Vts row stride (shorts)

__global__ __launch_bounds__(256, 2) void attn_kernel(const unsigned short* __restrict__ Q,
                                                      const unsigned short* __restrict__ Kv,
                                                      const unsigned short* __restrict__ Vt,
                                                      unsigned short* __restrict__ Y) {
    __shared__ unsigned short smem[128 * LD + 64 * LDV];   // 35840 B
    unsigned short* Ks = smem;                  // [key 0..127][d 0..63]
    unsigned short* Vts = smem + 128 * LD;      // [d 0..63][key 0..127] (per-16 permuted)

    int bid = blockIdx.x;
    int qt = bid >> 6;          // 8 q-tiles of 256 rows per head
    int bh = bid & 63;          // same-head blocks share an XCD (bid%8 == bh%8)
    int b = bh >> 4, hh = bh & 15;
    const unsigned short* qh = Q + (size_t)bh * T_ * DK_;
    const unsigned short* kh = Kv + (size_t)bh * T_ * DK_;
    const unsigned short* vtg = Vt + (size_t)bh * DK_ * T_;

    int tid = threadIdx.x, lane = tid & 63, w = tid >> 6;
    int l31 = lane & 31, h = lane >> 5;
    int qrA = qt * 256 + w * 32;
    int qrB = qrA + 128;

    // Q B-fragments held in registers: B[k=d][n=q], lane n=l31, k=16c+8h+j
    short8 qfA[4], qfB[4];
    for (int c = 0; c < 4; ++c) {
        qfA[c] = *(const short8*)&qh[(size_t)(qrA + l31) * DK_ + 16 * c + 8 * h];
        qfB[c] = *(const short8*)&qh[(size_t)(qrB + l31) * DK_ + 16 * c + 8 * h];
    }

    floatx16 oA0 = {}, oA1 = {}, oB0 = {}, oB1 = {};
    float lA = 0.f, lB = 0.f;

    for (int kt = 0; kt < T_; kt += KT) {
        __syncthreads();
        // stage 128 keys of K ([key][d]) and V^T ([d][key], per-16 permuted)
        for (int it = 0; it < 4; ++it) {
            int idx = tid + it * 256;                 // 0..1023
            int kr = idx >> 3, kc8 = (idx & 7) * 8;   // K: 128 rows x 8 chunks
            *(short8*)&Ks[kr * LD + kc8] = *(const short8*)&kh[(size_t)(kt + kr) * DK_ + kc8];
            int vr = idx >> 4, vc8 = (idx & 15) * 8;  // V: 64 rows x 16 chunks
            int vd = vr * LDV + (vc8 & 0x70) + ((vc8 & 8) >> 1);
            union { short8 s; short4v q[2]; } u;
            u.s = *(const short8*)&vtg[(size_t)vr * T_ + kt + vc8];
            *(short4v*)&Vts[vd] = u.q[0];
            *(short4v*)&Vts[vd + 8] = u.q[1];
        }
        __syncthreads();

#pragma unroll
        for (int hf = 0; hf < 2; ++hf) {
            int kb = hf * 64;
            // S^T = K . Q^T for both q-tiles; K-fragments shared
            floatx16 sA0 = {}, sA1 = {}, sB0 = {}, sB1 = {};
            for (int c = 0; c < 4; ++c) {
                short8 kf0 = *(const short8*)&Ks[(kb + l31) * LD + 16 * c + 8 * h];
                short8 kf1 = *(const short8*)&Ks[(kb + 32 + l31) * LD + 16 * c + 8 * h];
                sA0 = __builtin_amdgcn_mfma_f32_32x32x16_bf16(kf0, qfA[c], sA0, 0, 0, 0);
                sA1 = __builtin_amdgcn_mfma_f32_32x32x16_bf16(kf1, qfA[c], sA1, 0, 0, 0);
                sB0 = __builtin_amdgcn_mfma_f32_32x32x16_bf16(kf0, qfB[c], sB0, 0, 0, 0);
                sB1 = __builtin_amdgcn_mfma_f32_32x32x16_bf16(kf1, qfB[c], sB1, 0, 0, 0);
            }

            // exp2 (no max subtraction) + pack reg pairs -> B-frag dwords
            unsigned pA[16], pB[16];
            float tsA = 0.f, tsB = 0.f;
            for (int r2 = 0; r2 < 8; ++r2) {
                float a0 = __builtin_amdgcn_exp2f(sA0[2 * r2]);
                float a1 = __builtin_amdgcn_exp2f(sA0[2 * r2 + 1]);
                tsA += a0 + a1; pA[r2] = pack_bf16(a0, a1);
                float a2 = __builtin_amdgcn_exp2f(sA1[2 * r2]);
                float a3 = __builtin_amdgcn_exp2f(sA1[2 * r2 + 1]);
                tsA += a2 + a3; pA[8 + r2] = pack_bf16(a2, a3);
                float b0 = __builtin_amdgcn_exp2f(sB0[2 * r2]);
                float b1 = __builtin_amdgcn_exp2f(sB0[2 * r2 + 1]);
                tsB += b0 + b1; pB[r2] = pack_bf16(b0, b1);
                float b2 = __builtin_amdgcn_exp2f(sB1[2 * r2]);
                float b3 = __builtin_amdgcn_exp2f(sB1[2 * r2 + 1]);
                tsB += b2 + b3; pB[8 + r2] = pack_bf16(b2, b3);
            }
            lA += tsA; lB += tsB;

            // O^T += V^T . P^T with permuted key order; V-frags single b128
            for (int c = 0; c < 4; ++c) {
                short8 vf0 = *(const short8*)&Vts[l31 * LDV + kb + 16 * c + 8 * h];
                short8 vf1 = *(const short8*)&Vts[(32 + l31) * LDV + kb + 16 * c + 8 * h];
                union { unsigned u[4]; short8 s; } fA, fB;
                for (int j = 0; j < 4; ++j) { fA.u[j] = pA[4 * c + j]; fB.u[j] = pB[4 * c + j]; }
                oA0 = __builtin_amdgcn_mfma_f32_32x32x16_bf16(vf0, fA.s, oA0, 0, 0, 0);
                oA1 = __builtin_amdgcn_mfma_f32_32x32x16_bf16(vf1, fA.s, oA1, 0, 0, 0);
                oB0 = __builtin_amdgcn_mfma_f32_32x32x16_bf16(vf0, fB.s, oB0, 0, 0, 0);
                oB1 = __builtin_amdgcn_mfma_f32_32x32x16_bf16(vf1, fB.s, oB1, 0, 0, 0);
            }
        }
    }

    // finalize l across key-halves; normalize; 2 passes through reused smem
    float invA = 1.0f / (lA + __shfl_xor(lA, 32, 64));
    float invB = 1.0f / (lB + __shfl_xor(lB, 32, 64));
    int q_l = tid >> 1, seg = tid & 1;

    __syncthreads();
    for (int a = 0; a < 4; ++a) {
        ushort4 u;
        u.x = f2bf(oA0[4 * a + 0] * invA); u.y = f2bf(oA0[4 * a + 1] * invA);
        u.z = f2bf(oA0[4 * a + 2] * invA); u.w = f2bf(oA0[4 * a + 3] * invA);
        *(ushort4*)&smem[(w * 32 + l31) * LD + 8 * a + 4 * h] = u;
        ushort4 v;
        v.x = f2bf(oA1[4 * a + 0] * invA); v.y = f2bf(oA1[4 * a + 1] * invA);
        v.z = f2bf(oA1[4 * a + 2] * invA); v.w = f2bf(oA1[4 * a + 3] * invA);
        *(ushort4*)&smem[(w * 32 + l31) * LD + 32 + 8 * a + 4 * h] = v;
    }
    __syncthreads();
    {
        const unsigned short* srcp = &smem[(size_t)q_l * LD + seg * 32];
        unsigned short* dstp = &Y[((size_t)b * T_ + qt * 256 + q_l) * C_ + hh * DK_ + seg * 32];
        for (int j = 0; j < 4; ++j)
            *(short8*)&dstp[8 * j] = *(const short8*)&srcp[8 * j];
    }
    __syncthreads();
    for (int a = 0; a < 4; ++a) {
        ushort4 u;
        u.x = f2bf(oB0[4 * a + 0] * invB); u.y = f2bf(oB0[4 * a + 1] * invB);
        u.z = f2bf(oB0[4 * a + 2] * invB); u.w = f2bf(oB0[4 * a + 3] * invB);
        *(ushort4*)&smem[(w * 32 + l31) * LD + 8 * a + 4 * h] = u;
        ushort4 v;
        v.x = f2bf(oB1[4 * a + 0] * invB); v.y = f2bf(oB1[4 * a + 1] * invB);
        v.z = f2bf(oB1[4 * a + 2] * invB); v.w = f2bf(oB1[4 * a + 3] * invB);
        *(ushort4*)&smem[(w * 32 + l31) * LD + 32 + 8 * a + 4 * h] = v;
    }
    __syncthreads();
    {
        const unsigned short* srcp = &smem[(size_t)q_l * LD + seg * 32];
        unsigned short* dstp = &Y[((size_t)b * T_ + qt * 256 + 128 + q_l) * C_ + hh * DK_ + seg * 32];
        for (int j = 0; j < 4; ++j)
            *(short8*)&dstp[8 * j] = *(const short8*)&srcp[8 * j];
    }
}

extern "C" void kernel_launch(void* const* d_in, const int* in_sizes, int n_in,
                              void* d_out, int out_size, void* d_ws, size_t ws_size,
                              hipStream_t stream) {
    const float* x      = (const float*)d_in[0];
    const float* w_attn = (const float*)d_in[1];
    const float* b_attn = (const float*)d_in[2];
    const float* w_proj = (const float*)d_in[3];
    const float* b_proj = (const float*)d_in[4];
    float* out = (float*)d_out;

    unsigned short* ws = (unsigned short*)d_ws;
    unsigned short* xb  = ws;                       // 8192*1024
    unsigned short* wab = xb  + (size_t)M_ * C_;    // 3072*1024
    unsigned short* wpb = wab + (size_t)N3_ * C_;   // 1024*1024
    unsigned short* qb  = wpb + (size_t)C_ * C_;    // [B,H,T,dk]
    unsigned short* kb  = qb  + (size_t)M_ * C_;    // [B,H,T,dk]
    unsigned short* vb  = kb  + (size_t)M_ * C_;    // [B,H,dk,T] — written transposed
    unsigned short* yb  = vb  + (size_t)M_ * C_;    // 8192*1024

    cast3_kernel<<<(NX4 + NA4 + NP4) / 256, 256, 0, stream>>>(x, w_attn, w_proj, xb, wab, wpb);
    gemm_qkv<<<dim3(N3_ / BN, M_ / BM), 256, 0, stream>>>(xb, wab, b_attn, qb, kb, vb);
    attn_kernel<<<B_ * H_ * (T_ / 256), 256, 0, stream>>>(qb, kb, vb, yb);
    gemm_proj<<<dim3(C_ / BN, M_ / BM), 256, 0, stream>>>(yb, wpb, b_proj, out);
}

// Round 13
// 267.439 us; speedup vs baseline: 1.0592x; 1.0592x over previous
//
#include <hip/hip_runtime.h>
#include <hip/hip_bf16.h>

typedef __attribute__((ext_vector_type(8))) short short8;
typedef __attribute__((ext_vector_type(4))) short short4v;
typedef __attribute__((ext_vector_type(4))) float floatx4;
typedef __attribute__((ext_vector_type(16))) float floatx16;

#define B_ 4
#define T_ 2048
#define C_ 1024
#define H_ 16
#define DK_ 64
#define M_ (B_ * T_)   // 8192
#define N3_ (3 * C_)   // 3072

// scale(1/8) * log2(e): folds softmax scaling AND exp->exp2 conversion into Q
#define QSCALE 0.1803368801111243f

__device__ __forceinline__ unsigned short f2bf(float f) {
    union { float f; unsigned u; } v; v.f = f;
    unsigned r = v.u + 0x7fffu + ((v.u >> 16) & 1u);
    return (unsigned short)(r >> 16);
}
__device__ __forceinline__ unsigned fbits(float f) {
    union { float f; unsigned u; } v; v.f = f; return v.u;
}
// pack two f32 -> dword of two bf16 (lo = a, hi = b)
__device__ __forceinline__ unsigned pack_bf16(float a, float b) {
#if __has_builtin(__builtin_amdgcn_cvt_pk_bf16_f32)
    typedef __attribute__((ext_vector_type(2))) __bf16 bf16x2;
    bf16x2 r = __builtin_amdgcn_cvt_pk_bf16_f32(a, b);
    union { bf16x2 v; unsigned u; } c; c.v = r; return c.u;
#else
    return __builtin_amdgcn_perm(fbits(b) + 0x8000u, fbits(a) + 0x8000u, 0x07060302u);
#endif
}

__device__ __forceinline__ void gload_lds16(const unsigned short* g, unsigned short* l) {
    __builtin_amdgcn_global_load_lds(
        (const __attribute__((address_space(1))) unsigned int*)(const void*)g,
        (__attribute__((address_space(3))) unsigned int*)(void*)l, 16, 0, 0);
}

// ---------------- fused cast fp32 -> bf16 for x, w_attn, w_proj --------------
#define NX4 (M_ * C_ / 4)     // 2097152
#define NA4 (N3_ * C_ / 4)    //  786432
#define NP4 (C_ * C_ / 4)     //  262144
__global__ __launch_bounds__(256) void cast3_kernel(const float* __restrict__ x,
                                                    const float* __restrict__ wa,
                                                    const float* __restrict__ wp,
                                                    unsigned short* __restrict__ xb,
                                                    unsigned short* __restrict__ wab,
                                                    unsigned short* __restrict__ wpb) {
    int i = blockIdx.x * 256 + threadIdx.x;
    const float* src; unsigned short* dst; int j;
    if (i < NX4) { src = x; dst = xb; j = i; }
    else if (i < NX4 + NA4) { src = wa; dst = wab; j = i - NX4; }
    else { src = wp; dst = wpb; j = i - NX4 - NA4; }
    float4 v = ((const float4*)src)[j];
    ushort4 o;
    o.x = f2bf(v.x); o.y = f2bf(v.y); o.z = f2bf(v.z); o.w = f2bf(v.w);
    ((ushort4*)dst)[j] = o;
}

// ---------------- B^T GEMM: m97 structure, BK=64, XOR-swizzled LDS -----------
// R9/R11-verified config (best measured totals 262.3 / 258.9 us): conflicts 0,
// 16 barrier pairs, coalesced Q/K epilogue, V written transposed.
#define BM 128
#define BN 128
#define BK 64
#define ELD 132   // epilogue LDS row stride (shorts)

__global__ __launch_bounds__(256) void gemm_qkv(const unsigned short* __restrict__ A,
                                                const unsigned short* __restrict__ W,
                                                const float* __restrict__ bias,
                                                unsigned short* __restrict__ qout,
                                                unsigned short* __restrict__ kout,
                                                unsigned short* __restrict__ vout) {
    __shared__ unsigned short sh[BM * ELD];     // 33792 B; As/Bs carved below
    unsigned short* As = sh;                    // [128][64]
    unsigned short* Bs = sh + BM * BK;          // [128][64]

    int lin = blockIdx.y * gridDim.x + blockIdx.x;
    int cpx = (gridDim.x * gridDim.y) >> 3;
    int swz = (lin & 7) * cpx + (lin >> 3);
    int m0 = (swz / gridDim.x) * BM;
    int n0 = (swz % gridDim.x) * BN;
    int tid = threadIdx.x;
    int lane = tid & 63, w = tid >> 6;
    int wm = (w >> 1) * 64, wn = (w & 1) * 64;
    int l16 = lane & 15, quad = lane >> 4;
    int srow = lane >> 3;
    int scol = ((lane & 7) ^ srow) * 8;         // pre-swizzled global source chunk

    floatx4 acc[4][4] = {};
    for (int kt = 0; kt < C_; kt += BK) {
        __syncthreads();
        for (int t = 0; t < 4; ++t) {
            int rbase = w * 32 + t * 8;
            gload_lds16(&A[(size_t)(m0 + rbase + srow) * C_ + kt + scol], &As[rbase * BK]);
            gload_lds16(&W[(size_t)(n0 + rbase + srow) * C_ + kt + scol], &Bs[rbase * BK]);
        }
        __syncthreads();
#pragma unroll
        for (int kc = 0; kc < 2; ++kc) {
            int ch = ((kc * 4 + quad) ^ (l16 & 7)) * 8;
            short8 af[4], bf[4];
            for (int i = 0; i < 4; ++i)
                af[i] = *(const short8*)&As[(wm + 16 * i + l16) * BK + ch];
            for (int j = 0; j < 4; ++j)
                bf[j] = *(const short8*)&Bs[(wn + 16 * j + l16) * BK + ch];
            for (int i = 0; i < 4; ++i)
                for (int j = 0; j < 4; ++j)
                    acc[i][j] = __builtin_amdgcn_mfma_f32_16x16x32_bf16(af[i], bf[j], acc[i][j], 0, 0, 0);
        }
    }

    int secb = n0 >> 10;    // block-uniform section (BN=128 divides 1024)
    if (secb == 2) {
        // V transposed: [bh][d][t], 4 consecutive t -> one ushort4
        for (int i = 0; i < 4; ++i)
            for (int j = 0; j < 4; ++j) {
                int col = n0 + wn + 16 * j + l16;
                float bval = bias[col];
                int cc = col & 1023;
                int h = cc >> 6, d = cc & 63;
                int m = m0 + wm + 16 * i + quad * 4;
                int b = m >> 11, t = m & (T_ - 1);
                int bh = b * H_ + h;
                ushort4 o;
                o.x = f2bf(acc[i][j][0] + bval);
                o.y = f2bf(acc[i][j][1] + bval);
                o.z = f2bf(acc[i][j][2] + bval);
                o.w = f2bf(acc[i][j][3] + bval);
                *(ushort4*)&vout[((size_t)bh * DK_ + d) * T_ + t] = o;
            }
    } else {
        float qs = (secb == 0) ? QSCALE : 1.0f;
        unsigned short* dst = (secb == 0) ? qout : kout;
        __syncthreads();
        for (int i = 0; i < 4; ++i)
            for (int j = 0; j < 4; ++j) {
                int col = wn + 16 * j + l16;
                float bval = bias[n0 + col];
                for (int r = 0; r < 4; ++r) {
                    int row = wm + 16 * i + quad * 4 + r;
                    sh[row * ELD + col] = f2bf((acc[i][j][r] + bval) * qs);
                }
            }
        __syncthreads();
        for (int p = 0; p < 8; ++p) {
            int row = p * 16 + (tid >> 4);
            int cl = l16 * 8;
            short8 v = *(const short8*)&sh[row * ELD + cl];
            int cc = (n0 & 1023) + cl;
            int h = cc >> 6, d = cc & 63;
            int m = m0 + row, b = m >> 11, t = m & (T_ - 1);
            int bh = b * H_ + h;
            *(short8*)&dst[((size_t)bh * T_ + t) * DK_ + d] = v;
        }
    }
}

__global__ __launch_bounds__(256) void gemm_proj(const unsigned short* __restrict__ A,
                                                 const unsigned short* __restrict__ W,
                                                 const float* __restrict__ bias,
                                                 float* __restrict__ out) {
    __shared__ unsigned short As[BM * BK];
    __shared__ unsigned short Bs[BN * BK];
    int lin = blockIdx.y * gridDim.x + blockIdx.x;
    int cpx = (gridDim.x * gridDim.y) >> 3;
    int swz = (lin & 7) * cpx + (lin >> 3);
    int m0 = (swz / gridDim.x) * BM;
    int n0 = (swz % gridDim.x) * BN;
    int tid = threadIdx.x;
    int lane = tid & 63, w = tid >> 6;
    int wm = (w >> 1) * 64, wn = (w & 1) * 64;
    int l16 = lane & 15, quad = lane >> 4;
    int srow = lane >> 3;
    int scol = ((lane & 7) ^ srow) * 8;

    floatx4 acc[4][4] = {};
    for (int kt = 0; kt < C_; kt += BK) {
        __syncthreads();
        for (int t = 0; t < 4; ++t) {
            int rbase = w * 32 + t * 8;
            gload_lds16(&A[(size_t)(m0 + rbase + srow) * C_ + kt + scol], &As[rbase * BK]);
            gload_lds16(&W[(size_t)(n0 + rbase + srow) * C_ + kt + scol], &Bs[rbase * BK]);
        }
        __syncthreads();
#pragma unroll
        for (int kc = 0; kc < 2; ++kc) {
            int ch = ((kc * 4 + quad) ^ (l16 & 7)) * 8;
            short8 af[4], bf[4];
            for (int i = 0; i < 4; ++i)
                af[i] = *(const short8*)&As[(wm + 16 * i + l16) * BK + ch];
            for (int j = 0; j < 4; ++j)
                bf[j] = *(const short8*)&Bs[(wn + 16 * j + l16) * BK + ch];
            for (int i = 0; i < 4; ++i)
                for (int j = 0; j < 4; ++j)
                    acc[i][j] = __builtin_amdgcn_mfma_f32_16x16x32_bf16(af[i], bf[j], acc[i][j], 0, 0, 0);
        }
    }
    for (int i = 0; i < 4; ++i)
        for (int j = 0; j < 4; ++j) {
            int col = n0 + wn + 16 * j + l16;
            float bval = bias[col];
            for (int r = 0; r < 4; ++r) {
                int m = m0 + wm + 16 * i + quad * 4 + r;
                out[(size_t)m * C_ + col] = acc[i][j][r] + bval;
            }
        }
}

// ---------------- flash attention (R9/R11: XCD-local head mapping) -----------
// qt = bid>>6, bh = bid&63: the 8 q-tile blocks sharing head bh's K/V all
// satisfy bid%8 == bh%8 -> same XCD -> K/V re-reads are L2 hits (FETCH
// 139 -> 24.6 MB measured). All structural variants measured worse:
// R1 dbuf+setprio (+4), R2/R10 occupancy (+12/+3.5), R12 KT=128 (+17.5,
// LDV bank conflicts 197K->1.2M on the PV critical path). This form is
// the structure's floor (~82.5 us, stable across 3 runs).
#define KT 64
#define LD 72   // LDS row stride (shorts): 144 B, stride 36 dwords == 4 mod 32

__global__ __launch_bounds__(256, 2) void attn_kernel(const unsigned short* __restrict__ Q,
                                                      const unsigned short* __restrict__ Kv,
                                                      const unsigned short* __restrict__ Vt,
                                                      unsigned short* __restrict__ Y) {
    __shared__ unsigned short smem[128 * LD];   // rows 0..63 = Ks, 64..127 = Vts
    unsigned short* Ks = smem;                  // [key][d]
    unsigned short* Vts = smem + 64 * LD;       // [d][key] (per-16 permuted)

    int bid = blockIdx.x;
    int qt = bid >> 6;          // 8 q-tiles of 256 rows per head
    int bh = bid & 63;          // same-head blocks share an XCD (bid%8 == bh%8)
    int b = bh >> 4, hh = bh & 15;
    const unsigned short* qh = Q + (size_t)bh * T_ * DK_;
    const unsigned short* kh = Kv + (size_t)bh * T_ * DK_;
    const unsigned short* vtg = Vt + (size_t)bh * DK_ * T_;

    int tid = threadIdx.x, lane = tid & 63, w = tid >> 6;
    int l31 = lane & 31, h = lane >> 5;
    int qrA = qt * 256 + w * 32;
    int qrB = qrA + 128;

    // Q B-fragments held in registers: B[k=d][n=q], lane n=l31, k=16c+8h+j
    short8 qfA[4], qfB[4];
    for (int c = 0; c < 4; ++c) {
        qfA[c] = *(const short8*)&qh[(size_t)(qrA + l31) * DK_ + 16 * c + 8 * h];
        qfB[c] = *(const short8*)&qh[(size_t)(qrB + l31) * DK_ + 16 * c + 8 * h];
    }

    floatx16 oA0 = {}, oA1 = {}, oB0 = {}, oB1 = {};
    float lA = 0.f, lB = 0.f;

    for (int kt = 0; kt < T_; kt += KT) {
        __syncthreads();
        for (int it = 0; it < 2; ++it) {
            int idx = tid + it * 256;
            int r8 = idx >> 3, c8 = (idx & 7) * 8;
            *(short8*)&Ks[r8 * LD + c8] = *(const short8*)&kh[(size_t)(kt + r8) * DK_ + c8];
            // permuted V store: {0-3,8-11,4-7,12-15} within each 16-col group
            int vd = r8 * LD + (c8 & 48) + ((c8 & 8) >> 1);
            union { short8 s; short4v q[2]; } u;
            u.s = *(const short8*)&vtg[(size_t)r8 * T_ + kt + c8];
            *(short4v*)&Vts[vd] = u.q[0];
            *(short4v*)&Vts[vd + 8] = u.q[1];
        }
        __syncthreads();

        // S^T = K . Q^T for both q-tiles; K-fragments shared
        floatx16 sA0 = {}, sA1 = {}, sB0 = {}, sB1 = {};
        for (int c = 0; c < 4; ++c) {
            short8 kf0 = *(const short8*)&Ks[l31 * LD + 16 * c + 8 * h];
            short8 kf1 = *(const short8*)&Ks[(32 + l31) * LD + 16 * c + 8 * h];
            sA0 = __builtin_amdgcn_mfma_f32_32x32x16_bf16(kf0, qfA[c], sA0, 0, 0, 0);
            sA1 = __builtin_amdgcn_mfma_f32_32x32x16_bf16(kf1, qfA[c], sA1, 0, 0, 0);
            sB0 = __builtin_amdgcn_mfma_f32_32x32x16_bf16(kf0, qfB[c], sB0, 0, 0, 0);
            sB1 = __builtin_amdgcn_mfma_f32_32x32x16_bf16(kf1, qfB[c], sB1, 0, 0, 0);
        }

        // exp2 (no max subtraction) + pack consecutive reg pairs -> B-frag dwords.
        unsigned pA[16], pB[16];
        float tsA = 0.f, tsB = 0.f;
        for (int r2 = 0; r2 < 8; ++r2) {
            float a0 = __builtin_amdgcn_exp2f(sA0[2 * r2]);
            float a1 = __builtin_amdgcn_exp2f(sA0[2 * r2 + 1]);
            tsA += a0 + a1; pA[r2] = pack_bf16(a0, a1);
            float a2 = __builtin_amdgcn_exp2f(sA1[2 * r2]);
            float a3 = __builtin_amdgcn_exp2f(sA1[2 * r2 + 1]);
            tsA += a2 + a3; pA[8 + r2] = pack_bf16(a2, a3);
            float b0 = __builtin_amdgcn_exp2f(sB0[2 * r2]);
            float b1 = __builtin_amdgcn_exp2f(sB0[2 * r2 + 1]);
            tsB += b0 + b1; pB[r2] = pack_bf16(b0, b1);
            float b2 = __builtin_amdgcn_exp2f(sB1[2 * r2]);
            float b3 = __builtin_amdgcn_exp2f(sB1[2 * r2 + 1]);
            tsB += b2 + b3; pB[8 + r2] = pack_bf16(b2, b3);
        }
        lA += tsA; lB += tsB;

        // O^T += V^T . P^T with permuted key order; V-frags single b128
        for (int c = 0; c < 4; ++c) {
            short8 vf0 = *(const short8*)&Vts[l31 * LD + 16 * c + 8 * h];
            short8 vf1 = *(const short8*)&Vts[(32 + l31) * LD + 16 * c + 8 * h];
            union { unsigned u[4]; short8 s; } fA, fB;
            for (int j = 0; j < 4; ++j) { fA.u[j] = pA[4 * c + j]; fB.u[j] = pB[4 * c + j]; }
            oA0 = __builtin_amdgcn_mfma_f32_32x32x16_bf16(vf0, fA.s, oA0, 0, 0, 0);
            oA1 = __builtin_amdgcn_mfma_f32_32x32x16_bf16(vf1, fA.s, oA1, 0, 0, 0);
            oB0 = __builtin_amdgcn_mfma_f32_32x32x16_bf16(vf0, fB.s, oB0, 0, 0, 0);
            oB1 = __builtin_amdgcn_mfma_f32_32x32x16_bf16(vf1, fB.s, oB1, 0, 0, 0);
        }
    }

    // finalize l across key-halves; normalize; 2 passes through reused smem
    float invA = 1.0f / (lA + __shfl_xor(lA, 32, 64));
    float invB = 1.0f / (lB + __shfl_xor(lB, 32, 64));
    int q_l = tid >> 1, seg = tid & 1;

    __syncthreads();
    for (int a = 0; a < 4; ++a) {
        ushort4 u;
        u.x = f2bf(oA0[4 * a + 0] * invA); u.y = f2bf(oA0[4 * a + 1] * invA);
        u.z = f2bf(oA0[4 * a + 2] * invA); u.w = f2bf(oA0[4 * a + 3] * invA);
        *(ushort4*)&smem[(w * 32 + l31) * LD + 8 * a + 4 * h] = u;
        ushort4 v;
        v.x = f2bf(oA1[4 * a + 0] * invA); v.y = f2bf(oA1[4 * a + 1] * invA);
        v.z = f2bf(oA1[4 * a + 2] * invA); v.w = f2bf(oA1[4 * a + 3] * invA);
        *(ushort4*)&smem[(w * 32 + l31) * LD + 32 + 8 * a + 4 * h] = v;
    }
    __syncthreads();
    {
        const unsigned short* srcp = &smem[(size_t)q_l * LD + seg * 32];
        unsigned short* dstp = &Y[((size_t)b * T_ + qt * 256 + q_l) * C_ + hh * DK_ + seg * 32];
        for (int j = 0; j < 4; ++j)
            *(short8*)&dstp[8 * j] = *(const short8*)&srcp[8 * j];
    }
    __syncthreads();
    for (int a = 0; a < 4; ++a) {
        ushort4 u;
        u.x = f2bf(oB0[4 * a + 0] * invB); u.y = f2bf(oB0[4 * a + 1] * invB);
        u.z = f2bf(oB0[4 * a + 2] * invB); u.w = f2bf(oB0[4 * a + 3] * invB);
        *(ushort4*)&smem[(w * 32 + l31) * LD + 8 * a + 4 * h] = u;
        ushort4 v;
        v.x = f2bf(oB1[4 * a + 0] * invB); v.y = f2bf(oB1[4 * a + 1] * invB);
        v.z = f2bf(oB1[4 * a + 2] * invB); v.w = f2bf(oB1[4 * a + 3] * invB);
        *(ushort4*)&smem[(w * 32 + l31) * LD + 32 + 8 * a + 4 * h] = v;
    }
    __syncthreads();
    {
        const unsigned short* srcp = &smem[(size_t)q_l * LD + seg * 32];
        unsigned short* dstp = &Y[((size_t)b * T_ + qt * 256 + 128 + q_l) * C_ + hh * DK_ + seg * 32];
        for (int j = 0; j < 4; ++j)
            *(short8*)&dstp[8 * j] = *(const short8*)&srcp[8 * j];
    }
}

extern "C" void kernel_launch(void* const* d_in, const int* in_sizes, int n_in,
                              void* d_out, int out_size, void* d_ws, size_t ws_size,
                              hipStream_t stream) {
    const float* x      = (const float*)d_in[0];
    const float* w_attn = (const float*)d_in[1];
    const float* b_attn = (const float*)d_in[2];
    const float* w_proj = (const float*)d_in[3];
    const float* b_proj = (const float*)d_in[4];
    float* out = (float*)d_out;

    unsigned short* ws = (unsigned short*)d_ws;
    unsigned short* xb  = ws;                       // 8192*1024
    unsigned short* wab = xb  + (size_t)M_ * C_;    // 3072*1024
    unsigned short* wpb = wab + (size_t)N3_ * C_;   // 1024*1024
    unsigned short* qb  = wpb + (size_t)C_ * C_;    // [B,H,T,dk]
    unsigned short* kb  = qb  + (size_t)M_ * C_;    // [B,H,T,dk]
    unsigned short* vb  = kb  + (size_t)M_ * C_;    // [B,H,dk,T] — written transposed
    unsigned short* yb  = vb  + (size_t)M_ * C_;    // 8192*1024

    cast3_kernel<<<(NX4 + NA4 + NP4) / 256, 256, 0, stream>>>(x, w_attn, w_proj, xb, wab, wpb);
    gemm_qkv<<<dim3(N3_ / BN, M_ / BM), 256, 0, stream>>>(xb, wab, b_attn, qb, kb, vb);
    attn_kernel<<<B_ * H_ * (T_ / 256), 256, 0, stream>>>(qb, kb, vb, yb);
    gemm_proj<<<dim3(C_ / BN, M_ / BM), 256, 0, stream>>>(yb, wpb, b_proj, out);
}

// Round 14
// 258.177 us; speedup vs baseline: 1.0971x; 1.0359x over previous
//
#include <hip/hip_runtime.h>
#include <hip/hip_bf16.h>

typedef __attribute__((ext_vector_type(8))) short short8;
typedef __attribute__((ext_vector_type(4))) short short4v;
typedef __attribute__((ext_vector_type(4))) float floatx4;
typedef __attribute__((ext_vector_type(16))) float floatx16;

#define B_ 4
#define T_ 2048
#define C_ 1024
#define H_ 16
#define DK_ 64
#define M_ (B_ * T_)   // 8192
#define N3_ (3 * C_)   // 3072

// scale(1/8) * log2(e): folds softmax scaling AND exp->exp2 conversion into Q
#define QSCALE 0.1803368801111243f

__device__ __forceinline__ unsigned short f2bf(float f) {
    union { float f; unsigned u; } v; v.f = f;
    unsigned r = v.u + 0x7fffu + ((v.u >> 16) & 1u);
    return (unsigned short)(r >> 16);
}
__device__ __forceinline__ unsigned fbits(float f) {
    union { float f; unsigned u; } v; v.f = f; return v.u;
}
// pack two f32 -> dword of two bf16 (lo = a, hi = b)
__device__ __forceinline__ unsigned pack_bf16(float a, float b) {
#if __has_builtin(__builtin_amdgcn_cvt_pk_bf16_f32)
    typedef __attribute__((ext_vector_type(2))) __bf16 bf16x2;
    bf16x2 r = __builtin_amdgcn_cvt_pk_bf16_f32(a, b);
    union { bf16x2 v; unsigned u; } c; c.v = r; return c.u;
#else
    return __builtin_amdgcn_perm(fbits(b) + 0x8000u, fbits(a) + 0x8000u, 0x07060302u);
#endif
}

__device__ __forceinline__ void gload_lds16(const unsigned short* g, unsigned short* l) {
    __builtin_amdgcn_global_load_lds(
        (const __attribute__((address_space(1))) unsigned int*)(const void*)g,
        (__attribute__((address_space(3))) unsigned int*)(void*)l, 16, 0, 0);
}

// ---------------- fused cast fp32 -> bf16 for x, w_attn, w_proj --------------
#define NX4 (M_ * C_ / 4)     // 2097152
#define NA4 (N3_ * C_ / 4)    //  786432
#define NP4 (C_ * C_ / 4)     //  262144
__global__ __launch_bounds__(256) void cast3_kernel(const float* __restrict__ x,
                                                    const float* __restrict__ wa,
                                                    const float* __restrict__ wp,
                                                    unsigned short* __restrict__ xb,
                                                    unsigned short* __restrict__ wab,
                                                    unsigned short* __restrict__ wpb) {
    int i = blockIdx.x * 256 + threadIdx.x;
    const float* src; unsigned short* dst; int j;
    if (i < NX4) { src = x; dst = xb; j = i; }
    else if (i < NX4 + NA4) { src = wa; dst = wab; j = i - NX4; }
    else { src = wp; dst = wpb; j = i - NX4 - NA4; }
    float4 v = ((const float4*)src)[j];
    ushort4 o;
    o.x = f2bf(v.x); o.y = f2bf(v.y); o.z = f2bf(v.z); o.w = f2bf(v.w);
    ((ushort4*)dst)[j] = o;
}

// ---------------- B^T GEMM: m97 structure, BK=64, XOR-swizzled LDS -----------
// (R9/R11/R13-verified: conflicts 0, best totals 258.9/262.3/267.4. Unchanged.)
#define BM 128
#define BN 128
#define BK 64
#define ELD 132   // epilogue LDS row stride (shorts)

__global__ __launch_bounds__(256) void gemm_qkv(const unsigned short* __restrict__ A,
                                                const unsigned short* __restrict__ W,
                                                const float* __restrict__ bias,
                                                unsigned short* __restrict__ qout,
                                                unsigned short* __restrict__ kout,
                                                unsigned short* __restrict__ vout) {
    __shared__ unsigned short sh[BM * ELD];     // 33792 B; As/Bs carved below
    unsigned short* As = sh;                    // [128][64]
    unsigned short* Bs = sh + BM * BK;          // [128][64]

    int lin = blockIdx.y * gridDim.x + blockIdx.x;
    int cpx = (gridDim.x * gridDim.y) >> 3;
    int swz = (lin & 7) * cpx + (lin >> 3);
    int m0 = (swz / gridDim.x) * BM;
    int n0 = (swz % gridDim.x) * BN;
    int tid = threadIdx.x;
    int lane = tid & 63, w = tid >> 6;
    int wm = (w >> 1) * 64, wn = (w & 1) * 64;
    int l16 = lane & 15, quad = lane >> 4;
    int srow = lane >> 3;
    int scol = ((lane & 7) ^ srow) * 8;         // pre-swizzled global source chunk

    floatx4 acc[4][4] = {};
    for (int kt = 0; kt < C_; kt += BK) {
        __syncthreads();
        for (int t = 0; t < 4; ++t) {
            int rbase = w * 32 + t * 8;
            gload_lds16(&A[(size_t)(m0 + rbase + srow) * C_ + kt + scol], &As[rbase * BK]);
            gload_lds16(&W[(size_t)(n0 + rbase + srow) * C_ + kt + scol], &Bs[rbase * BK]);
        }
        __syncthreads();
#pragma unroll
        for (int kc = 0; kc < 2; ++kc) {
            int ch = ((kc * 4 + quad) ^ (l16 & 7)) * 8;
            short8 af[4], bf[4];
            for (int i = 0; i < 4; ++i)
                af[i] = *(const short8*)&As[(wm + 16 * i + l16) * BK + ch];
            for (int j = 0; j < 4; ++j)
                bf[j] = *(const short8*)&Bs[(wn + 16 * j + l16) * BK + ch];
            for (int i = 0; i < 4; ++i)
                for (int j = 0; j < 4; ++j)
                    acc[i][j] = __builtin_amdgcn_mfma_f32_16x16x32_bf16(af[i], bf[j], acc[i][j], 0, 0, 0);
        }
    }

    int secb = n0 >> 10;    // block-uniform section (BN=128 divides 1024)
    if (secb == 2) {
        // V transposed: [bh][d][t], 4 consecutive t -> one ushort4
        for (int i = 0; i < 4; ++i)
            for (int j = 0; j < 4; ++j) {
                int col = n0 + wn + 16 * j + l16;
                float bval = bias[col];
                int cc = col & 1023;
                int h = cc >> 6, d = cc & 63;
                int m = m0 + wm + 16 * i + quad * 4;
                int b = m >> 11, t = m & (T_ - 1);
                int bh = b * H_ + h;
                ushort4 o;
                o.x = f2bf(acc[i][j][0] + bval);
                o.y = f2bf(acc[i][j][1] + bval);
                o.z = f2bf(acc[i][j][2] + bval);
                o.w = f2bf(acc[i][j][3] + bval);
                *(ushort4*)&vout[((size_t)bh * DK_ + d) * T_ + t] = o;
            }
    } else {
        float qs = (secb == 0) ? QSCALE : 1.0f;
        unsigned short* dst = (secb == 0) ? qout : kout;
        __syncthreads();
        for (int i = 0; i < 4; ++i)
            for (int j = 0; j < 4; ++j) {
                int col = wn + 16 * j + l16;
                float bval = bias[n0 + col];
                for (int r = 0; r < 4; ++r) {
                    int row = wm + 16 * i + quad * 4 + r;
                    sh[row * ELD + col] = f2bf((acc[i][j][r] + bval) * qs);
                }
            }
        __syncthreads();
        for (int p = 0; p < 8; ++p) {
            int row = p * 16 + (tid >> 4);
            int cl = l16 * 8;
            short8 v = *(const short8*)&sh[row * ELD + cl];
            int cc = (n0 & 1023) + cl;
            int h = cc >> 6, d = cc & 63;
            int m = m0 + row, b = m >> 11, t = m & (T_ - 1);
            int bh = b * H_ + h;
            *(short8*)&dst[((size_t)bh * T_ + t) * DK_ + d] = v;
        }
    }
}

__global__ __launch_bounds__(256) void gemm_proj(const unsigned short* __restrict__ A,
                                                 const unsigned short* __restrict__ W,
                                                 const float* __restrict__ bias,
                                                 float* __restrict__ out) {
    __shared__ unsigned short As[BM * BK];
    __shared__ unsigned short Bs[BN * BK];
    int lin = blockIdx.y * gridDim.x + blockIdx.x;
    int cpx = (gridDim.x * gridDim.y) >> 3;
    int swz = (lin & 7) * cpx + (lin >> 3);
    int m0 = (swz / gridDim.x) * BM;
    int n0 = (swz % gridDim.x) * BN;
    int tid = threadIdx.x;
    int lane = tid & 63, w = tid >> 6;
    int wm = (w >> 1) * 64, wn = (w & 1) * 64;
    int l16 = lane & 15, quad = lane >> 4;
    int srow = lane >> 3;
    int scol = ((lane & 7) ^ srow) * 8;

    floatx4 acc[4][4] = {};
    for (int kt = 0; kt < C_; kt += BK) {
        __syncthreads();
        for (int t = 0; t < 4; ++t) {
            int rbase = w * 32 + t * 8;
            gload_lds16(&A[(size_t)(m0 + rbase + srow) * C_ + kt + scol], &As[rbase * BK]);
            gload_lds16(&W[(size_t)(n0 + rbase + srow) * C_ + kt + scol], &Bs[rbase * BK]);
        }
        __syncthreads();
#pragma unroll
        for (int kc = 0; kc < 2; ++kc) {
            int ch = ((kc * 4 + quad) ^ (l16 & 7)) * 8;
            short8 af[4], bf[4];
            for (int i = 0; i < 4; ++i)
                af[i] = *(const short8*)&As[(wm + 16 * i + l16) * BK + ch];
            for (int j = 0; j < 4; ++j)
                bf[j] = *(const short8*)&Bs[(wn + 16 * j + l16) * BK + ch];
            for (int i = 0; i < 4; ++i)
                for (int j = 0; j < 4; ++j)
                    acc[i][j] = __builtin_amdgcn_mfma_f32_16x16x32_bf16(af[i], bf[j], acc[i][j], 0, 0, 0);
        }
    }
    for (int i = 0; i < 4; ++i)
        for (int j = 0; j < 4; ++j) {
            int col = n0 + wn + 16 * j + l16;
            float bval = bias[col];
            for (int r = 0; r < 4; ++r) {
                int m = m0 + wm + 16 * i + quad * 4 + r;
                out[(size_t)m * C_ + col] = acc[i][j][r] + bval;
            }
        }
}

// ---------------- flash attention (R11 + K via global_load_lds) --------------
// ONLY change vs R11: K staging switches from reg round-trip (2 global b128 +
// 2 ds_write_b128 per thread/iter) to direct DMA via gload_lds16 into a
// LINEAR Ks[64][64] with the GEMM-proven XOR chunk involution:
//   LDS[row][q] holds global[row][q ^ (row&7)]
//   stage: source chunk (lane&7)^(lane>>3), dest linear (DMA requirement)
//   read:  chunk (2c+h) ^ (l31&7) at row l31 / 32+l31 ((32+l31)&7 == l31&7)
// Same strides and quarter-wave read geometry as gemm_qkv's measured-zero-
// conflict tile. V staging unchanged (permuted 8B-split store can't be DMA'd).
// Epilogue smem reuse unchanged (Ks 4096 + Vts 4608 shorts fit in the
// 9216-short epilogue footprint).
#define KT 64
#define LD 72   // Vts/epilogue row stride (shorts): 36 dwords == 4 mod 32

__global__ __launch_bounds__(256, 2) void attn_kernel(const unsigned short* __restrict__ Q,
                                                      const unsigned short* __restrict__ Kv,
                                                      const unsigned short* __restrict__ Vt,
                                                      unsigned short* __restrict__ Y) {
    __shared__ unsigned short smem[128 * LD];   // 18432 B (epilogue needs all)
    unsigned short* Ks = smem;                  // [key 0..63][d 0..63] linear, swizzled
    unsigned short* Vts = smem + 64 * 64;       // [d][key] (per-16 permuted), stride LD

    int bid = blockIdx.x;
    int qt = bid >> 6;          // 8 q-tiles of 256 rows per head
    int bh = bid & 63;          // same-head blocks share an XCD (bid%8 == bh%8)
    int b = bh >> 4, hh = bh & 15;
    const unsigned short* qh = Q + (size_t)bh * T_ * DK_;
    const unsigned short* kh = Kv + (size_t)bh * T_ * DK_;
    const unsigned short* vtg = Vt + (size_t)bh * DK_ * T_;

    int tid = threadIdx.x, lane = tid & 63, w = tid >> 6;
    int l31 = lane & 31, h = lane >> 5;
    int qrA = qt * 256 + w * 32;
    int qrB = qrA + 128;
    int srow = lane >> 3;                        // 0..7
    int scol = ((lane & 7) ^ srow) * 8;          // pre-swizzled K source chunk

    // Q B-fragments held in registers: B[k=d][n=q], lane n=l31, k=16c+8h+j
    short8 qfA[4], qfB[4];
    for (int c = 0; c < 4; ++c) {
        qfA[c] = *(const short8*)&qh[(size_t)(qrA + l31) * DK_ + 16 * c + 8 * h];
        qfB[c] = *(const short8*)&qh[(size_t)(qrB + l31) * DK_ + 16 * c + 8 * h];
    }

    floatx16 oA0 = {}, oA1 = {}, oB0 = {}, oB1 = {};
    float lA = 0.f, lB = 0.f;

    for (int kt = 0; kt < T_; kt += KT) {
        __syncthreads();
        // K: direct global->LDS DMA (wave w covers rows w*16 .. w*16+15)
        {
            int rbase = w * 16;
            gload_lds16(&kh[(size_t)(kt + rbase + srow) * DK_ + scol], &Ks[rbase * 64]);
            gload_lds16(&kh[(size_t)(kt + rbase + 8 + srow) * DK_ + scol], &Ks[(rbase + 8) * 64]);
        }
        // V: reg-staged permuted store {0-3,8-11,4-7,12-15} per 16-col group
        for (int it = 0; it < 2; ++it) {
            int idx = tid + it * 256;
            int r8 = idx >> 3, c8 = (idx & 7) * 8;
            int vd = r8 * LD + (c8 & 48) + ((c8 & 8) >> 1);
            union { short8 s; short4v q[2]; } u;
            u.s = *(const short8*)&vtg[(size_t)r8 * T_ + kt + c8];
            *(short4v*)&Vts[vd] = u.q[0];
            *(short4v*)&Vts[vd + 8] = u.q[1];
        }
        __syncthreads();

        // S^T = K . Q^T for both q-tiles; K-fragments shared, swizzled read
        floatx16 sA0 = {}, sA1 = {}, sB0 = {}, sB1 = {};
        for (int c = 0; c < 4; ++c) {
            int ch = ((2 * c + h) ^ (l31 & 7)) * 8;
            short8 kf0 = *(const short8*)&Ks[l31 * 64 + ch];
            short8 kf1 = *(const short8*)&Ks[(32 + l31) * 64 + ch];
            sA0 = __builtin_amdgcn_mfma_f32_32x32x16_bf16(kf0, qfA[c], sA0, 0, 0, 0);
            sA1 = __builtin_amdgcn_mfma_f32_32x32x16_bf16(kf1, qfA[c], sA1, 0, 0, 0);
            sB0 = __builtin_amdgcn_mfma_f32_32x32x16_bf16(kf0, qfB[c], sB0, 0, 0, 0);
            sB1 = __builtin_amdgcn_mfma_f32_32x32x16_bf16(kf1, qfB[c], sB1, 0, 0, 0);
        }

        // exp2 (no max subtraction) + pack consecutive reg pairs -> B-frag dwords.
        unsigned pA[16], pB[16];
        float tsA = 0.f, tsB = 0.f;
        for (int r2 = 0; r2 < 8; ++r2) {
            float a0 = __builtin_amdgcn_exp2f(sA0[2 * r2]);
            float a1 = __builtin_amdgcn_exp2f(sA0[2 * r2 + 1]);
            tsA += a0 + a1; pA[r2] = pack_bf16(a0, a1);
            float a2 = __builtin_amdgcn_exp2f(sA1[2 * r2]);
            float a3 = __builtin_amdgcn_exp2f(sA1[2 * r2 + 1]);
            tsA += a2 + a3; pA[8 + r2] = pack_bf16(a2, a3);
            float b0 = __builtin_amdgcn_exp2f(sB0[2 * r2]);
            float b1 = __builtin_amdgcn_exp2f(sB0[2 * r2 + 1]);
            tsB += b0 + b1; pB[r2] = pack_bf16(b0, b1);
            float b2 = __builtin_amdgcn_exp2f(sB1[2 * r2]);
            float b3 = __builtin_amdgcn_exp2f(sB1[2 * r2 + 1]);
            tsB += b2 + b3; pB[8 + r2] = pack_bf16(b2, b3);
        }
        lA += tsA; lB += tsB;

        // O^T += V^T . P^T with permuted key order; V-frags single b128
        for (int c = 0; c < 4; ++c) {
            short8 vf0 = *(const short8*)&Vts[l31 * LD + 16 * c + 8 * h];
            short8 vf1 = *(const short8*)&Vts[(32 + l31) * LD + 16 * c + 8 * h];
            union { unsigned u[4]; short8 s; } fA, fB;
            for (int j = 0; j < 4; ++j) { fA.u[j] = pA[4 * c + j]; fB.u[j] = pB[4 * c + j]; }
            oA0 = __builtin_amdgcn_mfma_f32_32x32x16_bf16(vf0, fA.s, oA0, 0, 0, 0);
            oA1 = __builtin_amdgcn_mfma_f32_32x32x16_bf16(vf1, fA.s, oA1, 0, 0, 0);
            oB0 = __builtin_amdgcn_mfma_f32_32x32x16_bf16(vf0, fB.s, oB0, 0, 0, 0);
            oB1 = __builtin_amdgcn_mfma_f32_32x32x16_bf16(vf1, fB.s, oB1, 0, 0, 0);
        }
    }

    // finalize l across key-halves; normalize; 2 passes through reused smem
    float invA = 1.0f / (lA + __shfl_xor(lA, 32, 64));
    float invB = 1.0f / (lB + __shfl_xor(lB, 32, 64));
    int q_l = tid >> 1, seg = tid & 1;

    __syncthreads();
    for (int a = 0; a < 4; ++a) {
        ushort4 u;
        u.x = f2bf(oA0[4 * a + 0] * invA); u.y = f2bf(oA0[4 * a + 1] * invA);
        u.z = f2bf(oA0[4 * a + 2] * invA); u.w = f2bf(oA0[4 * a + 3] * invA);
        *(ushort4*)&smem[(w * 32 + l31) * LD + 8 * a + 4 * h] = u;
        ushort4 v;
        v.x = f2bf(oA1[4 * a + 0] * invA); v.y = f2bf(oA1[4 * a + 1] * invA);
        v.z = f2bf(oA1[4 * a + 2] * invA); v.w = f2bf(oA1[4 * a + 3] * invA);
        *(ushort4*)&smem[(w * 32 + l31) * LD + 32 + 8 * a + 4 * h] = v;
    }
    __syncthreads();
    {
        const unsigned short* srcp = &smem[(size_t)q_l * LD + seg * 32];
        unsigned short* dstp = &Y[((size_t)b * T_ + qt * 256 + q_l) * C_ + hh * DK_ + seg * 32];
        for (int j = 0; j < 4; ++j)
            *(short8*)&dstp[8 * j] = *(const short8*)&srcp[8 * j];
    }
    __syncthreads();
    for (int a = 0; a < 4; ++a) {
        ushort4 u;
        u.x = f2bf(oB0[4 * a + 0] * invB); u.y = f2bf(oB0[4 * a + 1] * invB);
        u.z = f2bf(oB0[4 * a + 2] * invB); u.w = f2bf(oB0[4 * a + 3] * invB);
        *(ushort4*)&smem[(w * 32 + l31) * LD + 8 * a + 4 * h] = u;
        ushort4 v;
        v.x = f2bf(oB1[4 * a + 0] * invB); v.y = f2bf(oB1[4 * a + 1] * invB);
        v.z = f2bf(oB1[4 * a + 2] * invB); v.w = f2bf(oB1[4 * a + 3] * invB);
        *(ushort4*)&smem[(w * 32 + l31) * LD + 32 + 8 * a + 4 * h] = v;
    }
    __syncthreads();
    {
        const unsigned short* srcp = &smem[(size_t)q_l * LD + seg * 32];
        unsigned short* dstp = &Y[((size_t)b * T_ + qt * 256 + 128 + q_l) * C_ + hh * DK_ + seg * 32];
        for (int j = 0; j < 4; ++j)
            *(short8*)&dstp[8 * j] = *(const short8*)&srcp[8 * j];
    }
}

extern "C" void kernel_launch(void* const* d_in, const int* in_sizes, int n_in,
                              void* d_out, int out_size, void* d_ws, size_t ws_size,
                              hipStream_t stream) {
    const float* x      = (const float*)d_in[0];
    const float* w_attn = (const float*)d_in[1];
    const float* b_attn = (const float*)d_in[2];
    const float* w_proj = (const float*)d_in[3];
    const float* b_proj = (const float*)d_in[4];
    float* out = (float*)d_out;

    unsigned short* ws = (unsigned short*)d_ws;
    unsigned short* xb  = ws;                       // 8192*1024
    unsigned short* wab = xb  + (size_t)M_ * C_;    // 3072*1024
    unsigned short* wpb = wab + (size_t)N3_ * C_;   // 1024*1024
    unsigned short* qb  = wpb + (size_t)C_ * C_;    // [B,H,T,dk]
    unsigned short* kb  = qb  + (size_t)M_ * C_;    // [B,H,T,dk]
    unsigned short* vb  = kb  + (size_t)M_ * C_;    // [B,H,dk,T] — written transposed
    unsigned short* yb  = vb  + (size_t)M_ * C_;    // 8192*1024

    cast3_kernel<<<(NX4 + NA4 + NP4) / 256, 256, 0, stream>>>(x, w_attn, w_proj, xb, wab, wpb);
    gemm_qkv<<<dim3(N3_ / BN, M_ / BM), 256, 0, stream>>>(xb, wab, b_attn, qb, kb, vb);
    attn_kernel<<<B_ * H_ * (T_ / 256), 256, 0, stream>>>(qb, kb, vb, yb);
    gemm_proj<<<dim3(C_ / BN, M_ / BM), 256, 0, stream>>>(yb, wpb, b_proj, out);
}